// Round 3
// baseline (208.377 us; speedup 1.0000x reference)
//
#include <hip/hip_runtime.h>

#define B_ 16
#define N_ 8192
#define D_ 64

__device__ __forceinline__ float elu1(float x) {
    // F.elu(x)+1 == x+1 for x>0, exp(x) otherwise
    return x > 0.0f ? x + 1.0f : __expf(x);
}

// ---------------------------------------------------------------------------
// Pass 1: partial KV per N-chunk.  grid = B_*C blocks, 256 threads.
// Each block: rows [c*R, c*R+R) of batch b; accumulates 64x64 partial
// KV = phi(k)^T @ v in registers (4x4 per thread), writes to part[bid].
// ---------------------------------------------------------------------------
template <int TI>
__global__ __launch_bounds__(256) void k1_partial(const float* __restrict__ kin,
                                                  const float* __restrict__ vin,
                                                  float* __restrict__ part,
                                                  int C, int R) {
    const int bid = blockIdx.x;
    const int b = bid / C, c = bid % C;
    const size_t base = ((size_t)b * N_ + (size_t)c * R) * D_;
    const float4* kp = (const float4*)(kin + base);
    const float4* vp = (const float4*)(vin + base);

    __shared__ float lk[TI][D_];
    __shared__ float lv[TI][D_];

    const int tid = threadIdx.x;
    const int td = tid >> 4;   // 0..15 -> owns d rows 4*td..4*td+3
    const int te = tid & 15;   // 0..15 -> owns e cols 4*te..4*te+3

    float acc[4][4];
#pragma unroll
    for (int i = 0; i < 4; ++i)
#pragma unroll
        for (int j = 0; j < 4; ++j) acc[i][j] = 0.0f;

    const int ntiles = R / TI;
    for (int t = 0; t < ntiles; ++t) {
        // stage TI rows of k (elu'd) and v into LDS, coalesced float4
#pragma unroll
        for (int u = tid; u < TI * (D_ / 4); u += 256) {
            float4 kk = kp[t * TI * (D_ / 4) + u];
            float4 vv = vp[t * TI * (D_ / 4) + u];
            const int r = u >> 4, cc = (u & 15) * 4;
            float4 ek;
            ek.x = elu1(kk.x); ek.y = elu1(kk.y);
            ek.z = elu1(kk.z); ek.w = elu1(kk.w);
            *(float4*)&lk[r][cc] = ek;
            *(float4*)&lv[r][cc] = vv;
        }
        __syncthreads();
#pragma unroll 8
        for (int r = 0; r < TI; ++r) {
            const float4 kk = *(const float4*)&lk[r][td * 4];
            const float4 vv = *(const float4*)&lv[r][te * 4];
            const float kd[4] = {kk.x, kk.y, kk.z, kk.w};
            const float ve[4] = {vv.x, vv.y, vv.z, vv.w};
#pragma unroll
            for (int i = 0; i < 4; ++i)
#pragma unroll
                for (int j = 0; j < 4; ++j)
                    acc[i][j] = __fmaf_rn(kd[i], ve[j], acc[i][j]);
        }
        __syncthreads();
    }

    float* pb = part + (size_t)bid * (D_ * D_);
#pragma unroll
    for (int i = 0; i < 4; ++i) {
        float4 o = {acc[i][0], acc[i][1], acc[i][2], acc[i][3]};
        *(float4*)&pb[(4 * td + i) * D_ + 4 * te] = o;
    }
}

// Atomic fallback (only if ws too small for partials): needs ws pre-zeroed.
template <int TI>
__global__ __launch_bounds__(256) void k1_atomic(const float* __restrict__ kin,
                                                 const float* __restrict__ vin,
                                                 float* __restrict__ kv,
                                                 int C, int R) {
    const int bid = blockIdx.x;
    const int b = bid / C, c = bid % C;
    const size_t base = ((size_t)b * N_ + (size_t)c * R) * D_;
    const float4* kp = (const float4*)(kin + base);
    const float4* vp = (const float4*)(vin + base);

    __shared__ float lk[TI][D_];
    __shared__ float lv[TI][D_];

    const int tid = threadIdx.x;
    const int td = tid >> 4;
    const int te = tid & 15;

    float acc[4][4];
#pragma unroll
    for (int i = 0; i < 4; ++i)
#pragma unroll
        for (int j = 0; j < 4; ++j) acc[i][j] = 0.0f;

    const int ntiles = R / TI;
    for (int t = 0; t < ntiles; ++t) {
#pragma unroll
        for (int u = tid; u < TI * (D_ / 4); u += 256) {
            float4 kk = kp[t * TI * (D_ / 4) + u];
            float4 vv = vp[t * TI * (D_ / 4) + u];
            const int r = u >> 4, cc = (u & 15) * 4;
            float4 ek;
            ek.x = elu1(kk.x); ek.y = elu1(kk.y);
            ek.z = elu1(kk.z); ek.w = elu1(kk.w);
            *(float4*)&lk[r][cc] = ek;
            *(float4*)&lv[r][cc] = vv;
        }
        __syncthreads();
#pragma unroll 8
        for (int r = 0; r < TI; ++r) {
            const float4 kk = *(const float4*)&lk[r][td * 4];
            const float4 vv = *(const float4*)&lv[r][te * 4];
            const float kd[4] = {kk.x, kk.y, kk.z, kk.w};
            const float ve[4] = {vv.x, vv.y, vv.z, vv.w};
#pragma unroll
            for (int i = 0; i < 4; ++i)
#pragma unroll
                for (int j = 0; j < 4; ++j)
                    acc[i][j] = __fmaf_rn(kd[i], ve[j], acc[i][j]);
        }
        __syncthreads();
    }

    float* pb = kv + (size_t)b * (D_ * D_);
#pragma unroll
    for (int i = 0; i < 4; ++i)
#pragma unroll
        for (int j = 0; j < 4; ++j)
            atomicAdd(&pb[(4 * td + i) * D_ + 4 * te + j], acc[i][j]);
}

// ---------------------------------------------------------------------------
// Pass 1b: reduce C partials -> final KV written in-place to chunk 0.
// ---------------------------------------------------------------------------
__global__ __launch_bounds__(256) void k2_reduce(float* __restrict__ part, int C) {
    const int i = blockIdx.x * 256 + threadIdx.x;  // 0 .. B_*4096-1
    const int b = i >> 12, j = i & 4095;
    float* p = part + (size_t)b * C * (D_ * D_) + j;
    float s = 0.0f;
    for (int c = 0; c < C; ++c) s += p[(size_t)c * (D_ * D_)];
    p[0] = s;
}

// ---------------------------------------------------------------------------
// Pass 2: out[b,n,:] = phi(q[b,n,:]) @ KV[b] * (1/(D*N)).
// One thread per row; KV staged in LDS, read as wave-uniform broadcasts.
// ---------------------------------------------------------------------------
__global__ __launch_bounds__(256) void k3_out(const float* __restrict__ q,
                                              const float* __restrict__ kvbuf,
                                              size_t kvstride,
                                              float* __restrict__ out) {
    const int bpb = N_ / 256;  // blocks per batch
    const int b = blockIdx.x / bpb;
    const int n0 = (blockIdx.x % bpb) * 256;

    __shared__ float skv[D_ * D_];
    const float4* kp = (const float4*)(kvbuf + (size_t)b * kvstride);
#pragma unroll
    for (int u = threadIdx.x; u < (D_ * D_) / 4; u += 256)
        *(float4*)&skv[u * 4] = kp[u];
    __syncthreads();

    const size_t row = (size_t)b * N_ + n0 + threadIdx.x;
    const float4* qp = (const float4*)(q + row * D_);

    float qf[D_];
#pragma unroll
    for (int j = 0; j < D_ / 4; ++j) {
        float4 t = qp[j];
        qf[4 * j + 0] = elu1(t.x);
        qf[4 * j + 1] = elu1(t.y);
        qf[4 * j + 2] = elu1(t.z);
        qf[4 * j + 3] = elu1(t.w);
    }

    float acc[D_];
#pragma unroll
    for (int e = 0; e < D_; ++e) acc[e] = 0.0f;

#pragma unroll 4
    for (int d = 0; d < D_; ++d) {
        const float qd = qf[d];
#pragma unroll
        for (int e4 = 0; e4 < D_ / 4; ++e4) {
            const float4 kvv = *(const float4*)&skv[d * D_ + e4 * 4];
            acc[4 * e4 + 0] = __fmaf_rn(qd, kvv.x, acc[4 * e4 + 0]);
            acc[4 * e4 + 1] = __fmaf_rn(qd, kvv.y, acc[4 * e4 + 1]);
            acc[4 * e4 + 2] = __fmaf_rn(qd, kvv.z, acc[4 * e4 + 2]);
            acc[4 * e4 + 3] = __fmaf_rn(qd, kvv.w, acc[4 * e4 + 3]);
        }
    }

    const float scale = 1.0f / (float)((size_t)D_ * N_);
    float4* op = (float4*)(out + row * D_);
#pragma unroll
    for (int j = 0; j < D_ / 4; ++j) {
        float4 o = {acc[4 * j + 0] * scale, acc[4 * j + 1] * scale,
                    acc[4 * j + 2] * scale, acc[4 * j + 3] * scale};
        op[j] = o;
    }
}

extern "C" void kernel_launch(void* const* d_in, const int* in_sizes, int n_in,
                              void* d_out, int out_size, void* d_ws, size_t ws_size,
                              hipStream_t stream) {
    const float* q = (const float*)d_in[0];
    const float* k = (const float*)d_in[1];
    const float* v = (const float*)d_in[2];
    float* out = (float*)d_out;
    float* ws = (float*)d_ws;

    const size_t mat = (size_t)D_ * D_;  // 4096 floats per KV matrix

    // pick largest chunk count whose partial buffer fits in ws
    int C = 0;
    for (int cc = 64; cc >= 2; cc >>= 1) {
        if (ws_size >= (size_t)B_ * cc * mat * sizeof(float)) { C = cc; break; }
    }

    if (C >= 2) {
        const int R = N_ / C;
        k1_partial<32><<<B_ * C, 256, 0, stream>>>(k, v, ws, C, R);
        k2_reduce<<<(int)(B_ * mat) / 256, 256, 0, stream>>>(ws, C);
        k3_out<<<B_ * (N_ / 256), 256, 0, stream>>>(q, ws, (size_t)C * mat, out);
    } else {
        // tiny-ws fallback: zero KV then atomically accumulate
        hipMemsetAsync(d_ws, 0, B_ * mat * sizeof(float), stream);
        const int C2 = 64, R = N_ / C2;
        k1_atomic<32><<<B_ * C2, 256, 0, stream>>>(k, v, ws, C2, R);
        k3_out<<<B_ * (N_ / 256), 256, 0, stream>>>(q, ws, mat, out);
    }
}

// Round 6
// 175.470 us; speedup vs baseline: 1.1875x; 1.1875x over previous
//
#include <hip/hip_runtime.h>

#define B_ 16
#define N_ 8192
#define D_ 64

__device__ __forceinline__ float elu1(float x) {
    // F.elu(x)+1 == x+1 for x>0, exp(x) otherwise
    return x > 0.0f ? x + 1.0f : __expf(x);
}

// ---------------------------------------------------------------------------
// Pass 1 (v2): wave-autonomous partial KV.
// grid = B_*C blocks, 256 threads (4 independent waves, no staging barriers).
// Each wave: 8x8 acc tile per lane (lane = (dq,eq) in 8x8), covers full 64x64.
// Rows fed 4-at-a-time by coalesced float4 loads + __shfl distribution.
// elu applied ONCE at load. Block-level LDS reduce -> one partial per block.
// ---------------------------------------------------------------------------
__global__ __launch_bounds__(256, 4) void k1_partial(const float* __restrict__ kin,
                                                     const float* __restrict__ vin,
                                                     float* __restrict__ part,
                                                     int C, int R) {
    const int bid = blockIdx.x;
    const int b = bid / C, c = bid % C;
    const int w = threadIdx.x >> 6;       // wave 0..3
    const int lane = threadIdx.x & 63;
    const int dq = lane >> 3;             // owns d in [8dq, 8dq+8)
    const int eq = lane & 7;              // owns e in [8eq, 8eq+8)

    const int rows_per_wave = R >> 2;     // R/4
    const size_t rowbase = (size_t)b * N_ + (size_t)c * R + (size_t)w * rows_per_wave;
    const float4* kp = (const float4*)(kin + rowbase * D_);
    const float4* vp = (const float4*)(vin + rowbase * D_);

    float acc[8][8];
#pragma unroll
    for (int i = 0; i < 8; ++i)
#pragma unroll
        for (int jj = 0; jj < 8; ++jj) acc[i][jj] = 0.0f;

    const int ngroups = rows_per_wave >> 2;   // 4 rows per group
    for (int g = 0; g < ngroups; ++g) {
        // wave loads 4 rows of k and v: lane -> row (lane>>4), quad (lane&15)
        float4 k4 = kp[g * 64 + lane];
        float4 v4 = vp[g * 64 + lane];
        k4.x = elu1(k4.x); k4.y = elu1(k4.y); k4.z = elu1(k4.z); k4.w = elu1(k4.w);
        const float ka[4] = {k4.x, k4.y, k4.z, k4.w};
        const float va[4] = {v4.x, v4.y, v4.z, v4.w};

#pragma unroll
        for (int rr = 0; rr < 4; ++rr) {
            const int sk0 = rr * 16 + 2 * dq;   // owner lane of k quads 2dq,2dq+1
            const int sv0 = rr * 16 + 2 * eq;
            float kk[8], vv[8];
#pragma unroll
            for (int cc = 0; cc < 4; ++cc) {
                kk[cc]     = __shfl(ka[cc], sk0,     64);
                kk[cc + 4] = __shfl(ka[cc], sk0 + 1, 64);
                vv[cc]     = __shfl(va[cc], sv0,     64);
                vv[cc + 4] = __shfl(va[cc], sv0 + 1, 64);
            }
#pragma unroll
            for (int i = 0; i < 8; ++i)
#pragma unroll
                for (int jj = 0; jj < 8; ++jj)
                    acc[i][jj] = __fmaf_rn(kk[i], vv[jj], acc[i][jj]);
        }
    }

    // cross-wave reduction in LDS (layout d*64+e); serial over 4 waves
    __shared__ float red[D_ * D_];
    for (int ww = 0; ww < 4; ++ww) {
        if (w == ww) {
#pragma unroll
            for (int i = 0; i < 8; ++i)
#pragma unroll
                for (int jq = 0; jq < 2; ++jq) {
                    float* p = &red[(8 * dq + i) * D_ + 8 * eq + 4 * jq];
                    if (ww == 0) {
                        float4 o = {acc[i][4 * jq + 0], acc[i][4 * jq + 1],
                                    acc[i][4 * jq + 2], acc[i][4 * jq + 3]};
                        *(float4*)p = o;
                    } else {
                        float4 cur = *(const float4*)p;
                        float4 o = {cur.x + acc[i][4 * jq + 0], cur.y + acc[i][4 * jq + 1],
                                    cur.z + acc[i][4 * jq + 2], cur.w + acc[i][4 * jq + 3]};
                        *(float4*)p = o;
                    }
                }
        }
        __syncthreads();
    }

    float4* pb = (float4*)(part + (size_t)bid * (D_ * D_));
    const float4* rp = (const float4*)red;
#pragma unroll
    for (int u = 0; u < 4; ++u)
        pb[threadIdx.x + 256 * u] = rp[threadIdx.x + 256 * u];
}

// ---------------------------------------------------------------------------
// Atomic fallback (only if ws too small for partials): needs ws pre-zeroed.
// ---------------------------------------------------------------------------
template <int TI>
__global__ __launch_bounds__(256) void k1_atomic(const float* __restrict__ kin,
                                                 const float* __restrict__ vin,
                                                 float* __restrict__ kv,
                                                 int C, int R) {
    const int bid = blockIdx.x;
    const int b = bid / C, c = bid % C;
    const size_t base = ((size_t)b * N_ + (size_t)c * R) * D_;
    const float4* kp = (const float4*)(kin + base);
    const float4* vp = (const float4*)(vin + base);

    __shared__ float lk[TI][D_];
    __shared__ float lv[TI][D_];

    const int tid = threadIdx.x;
    const int td = tid >> 4;
    const int te = tid & 15;

    float acc[4][4];
#pragma unroll
    for (int i = 0; i < 4; ++i)
#pragma unroll
        for (int j = 0; j < 4; ++j) acc[i][j] = 0.0f;

    const int ntiles = R / TI;
    for (int t = 0; t < ntiles; ++t) {
#pragma unroll
        for (int u = tid; u < TI * (D_ / 4); u += 256) {
            float4 kk = kp[t * TI * (D_ / 4) + u];
            float4 vv = vp[t * TI * (D_ / 4) + u];
            const int r = u >> 4, cc = (u & 15) * 4;
            float4 ek;
            ek.x = elu1(kk.x); ek.y = elu1(kk.y);
            ek.z = elu1(kk.z); ek.w = elu1(kk.w);
            *(float4*)&lk[r][cc] = ek;
            *(float4*)&lv[r][cc] = vv;
        }
        __syncthreads();
#pragma unroll 8
        for (int r = 0; r < TI; ++r) {
            const float4 kk = *(const float4*)&lk[r][td * 4];
            const float4 vv = *(const float4*)&lv[r][te * 4];
            const float kd[4] = {kk.x, kk.y, kk.z, kk.w};
            const float ve[4] = {vv.x, vv.y, vv.z, vv.w};
#pragma unroll
            for (int i = 0; i < 4; ++i)
#pragma unroll
                for (int j = 0; j < 4; ++j)
                    acc[i][j] = __fmaf_rn(kd[i], ve[j], acc[i][j]);
        }
        __syncthreads();
    }

    float* pb = kv + (size_t)b * (D_ * D_);
#pragma unroll
    for (int i = 0; i < 4; ++i)
#pragma unroll
        for (int j = 0; j < 4; ++j)
            atomicAdd(&pb[(4 * td + i) * D_ + 4 * te + j], acc[i][j]);
}

// ---------------------------------------------------------------------------
// Pass 1b: reduce C partials -> final KV written in-place to chunk 0.
// 4-way independent partial sums for load pipelining.
// ---------------------------------------------------------------------------
__global__ __launch_bounds__(256) void k2_reduce(float* __restrict__ part, int C) {
    const int i = blockIdx.x * 256 + threadIdx.x;  // 0 .. B_*4096-1
    const int b = i >> 12, jj = i & 4095;
    float* p = part + (size_t)b * C * (D_ * D_) + jj;
    float s0 = 0.0f, s1 = 0.0f, s2 = 0.0f, s3 = 0.0f;
    int c = 0;
    for (; c + 4 <= C; c += 4) {
        s0 += p[(size_t)(c + 0) * (D_ * D_)];
        s1 += p[(size_t)(c + 1) * (D_ * D_)];
        s2 += p[(size_t)(c + 2) * (D_ * D_)];
        s3 += p[(size_t)(c + 3) * (D_ * D_)];
    }
    for (; c < C; ++c) s0 += p[(size_t)c * (D_ * D_)];
    p[0] = (s0 + s1) + (s2 + s3);
}

// ---------------------------------------------------------------------------
// Pass 2 (v2): out[b,n,:] = phi(q[b,n,:]) @ KV[b] * (1/(D*N)).
// 4 lanes per row: tid -> (r = tid>>2, j = tid&3). Lane loads
// q[row][16j..16j+16) (64B contiguous/lane), owns interleaved e-quads
// {4j+16s : s=0..3} so every store instr is lane-unit-stride 16B (full
// 64B lines -> no write amplification). qf[d] broadcast via __shfl(.,d0,4).
// KV staged once in LDS, read as 4-address broadcast b128 (2-way alias, free).
// 64 rows/block -> grid 2048 (8 blocks/CU).
// ---------------------------------------------------------------------------
__global__ __launch_bounds__(256, 4) void k3_out(const float* __restrict__ q,
                                                 const float* __restrict__ kvbuf,
                                                 int kvstride,
                                                 float* __restrict__ out) {
    __shared__ float skv[D_ * D_];
    const int b = blockIdx.x >> 7;        // 128 blocks per batch
    const int tile = blockIdx.x & 127;

    // stage KV coalesced
    const float4* kvg = (const float4*)(kvbuf + (size_t)b * kvstride);
    float4* skv4 = (float4*)skv;
#pragma unroll
    for (int u = 0; u < 4; ++u)
        skv4[threadIdx.x + 256 * u] = kvg[threadIdx.x + 256 * u];

    const int r = threadIdx.x >> 2;       // 0..63 local row
    const int j = threadIdx.x & 3;
    const size_t row = (size_t)b * N_ + (size_t)tile * 64 + r;

    // load this lane's 16 q values (contiguous 64B) + elu
    const float4* qp = (const float4*)(q + row * D_ + j * 16);
    float qf[16];
#pragma unroll
    for (int u = 0; u < 4; ++u) {
        float4 t = qp[u];
        qf[4 * u + 0] = elu1(t.x);
        qf[4 * u + 1] = elu1(t.y);
        qf[4 * u + 2] = elu1(t.z);
        qf[4 * u + 3] = elu1(t.w);
    }
    __syncthreads();

    float4 acc[4];
#pragma unroll
    for (int s = 0; s < 4; ++s) acc[s] = {0.0f, 0.0f, 0.0f, 0.0f};

    for (int d0 = 0; d0 < 4; ++d0) {
        const int dbase = d0 * 16;
#pragma unroll
        for (int dd = 0; dd < 16; ++dd) {
            // qf[d] lives in lane (groupbase + d>>4) at local index d&15;
            // here d = d0*16+dd so owner = d0 (uniform), local = dd (static)
            const float qd = __shfl(qf[dd], d0, 4);
            const int d = dbase + dd;
#pragma unroll
            for (int s = 0; s < 4; ++s) {
                const float4 kvv = *(const float4*)&skv[d * D_ + s * 16 + j * 4];
                acc[s].x = __fmaf_rn(qd, kvv.x, acc[s].x);
                acc[s].y = __fmaf_rn(qd, kvv.y, acc[s].y);
                acc[s].z = __fmaf_rn(qd, kvv.z, acc[s].z);
                acc[s].w = __fmaf_rn(qd, kvv.w, acc[s].w);
            }
        }
    }

    const float scale = 1.0f / (float)((size_t)D_ * N_);
    float4* op = (float4*)(out + row * D_);
#pragma unroll
    for (int s = 0; s < 4; ++s) {
        float4 o = {acc[s].x * scale, acc[s].y * scale,
                    acc[s].z * scale, acc[s].w * scale};
        op[s * 4 + j] = o;   // e-quad (4j+16s) -> float4 index s*4+j
    }
}

extern "C" void kernel_launch(void* const* d_in, const int* in_sizes, int n_in,
                              void* d_out, int out_size, void* d_ws, size_t ws_size,
                              hipStream_t stream) {
    const float* q = (const float*)d_in[0];
    const float* k = (const float*)d_in[1];
    const float* v = (const float*)d_in[2];
    float* out = (float*)d_out;
    float* ws = (float*)d_ws;

    const size_t mat = (size_t)D_ * D_;  // 4096 floats per KV matrix

    // pick largest chunk count whose partial buffer fits in ws
    int C = 0;
    for (int cc = 64; cc >= 2; cc >>= 1) {
        if (ws_size >= (size_t)B_ * cc * mat * sizeof(float)) { C = cc; break; }
    }

    if (C >= 2) {
        const int R = N_ / C;
        k1_partial<<<B_ * C, 256, 0, stream>>>(k, v, ws, C, R);
        k2_reduce<<<(int)(B_ * mat) / 256, 256, 0, stream>>>(ws, C);
        k3_out<<<B_ * (N_ / 64), 256, 0, stream>>>(q, ws, (int)(C * mat), out);
    } else {
        // tiny-ws fallback: zero KV then atomically accumulate
        hipMemsetAsync(d_ws, 0, B_ * mat * sizeof(float), stream);
        const int C2 = 64, R = N_ / C2;
        k1_atomic<32><<<B_ * C2, 256, 0, stream>>>(k, v, ws, C2, R);
        k3_out<<<B_ * (N_ / 64), 256, 0, stream>>>(q, ws, (int)mat, out);
    }
}

// Round 8
// 172.210 us; speedup vs baseline: 1.2100x; 1.0189x over previous
//
#include <hip/hip_runtime.h>

#define B_ 16
#define N_ 8192
#define D_ 64

__device__ __forceinline__ float elu1(float x) {
    // F.elu(x)+1 == x+1 for x>0, exp(x) otherwise
    return x > 0.0f ? x + 1.0f : __expf(x);
}

// ---------------------------------------------------------------------------
// Pass 1 (v3): wave-autonomous partial KV, direct broadcast loads (no shfl).
// grid = B_*C blocks, 256 threads (4 waves). Each wave owns rows
// [w*R/4, (w+1)*R/4) and the FULL 64x64 KV tile: lane (dq,eq) holds
// acc[8][8] for d in [8dq,8dq+8), e in [8eq,8eq+8). Per row each lane
// loads its own 8 k-floats + 8 v-floats from global (8 lanes share each
// 32B segment -> coalescer/L1 broadcast; each byte fetched once from HBM).
// No cross-lane ops, no barriers in the main loop. Cross-wave LDS reduce
// at the end (one-time, cheap).
// ---------------------------------------------------------------------------
__global__ __launch_bounds__(256, 4) void k1_partial(const float* __restrict__ kin,
                                                     const float* __restrict__ vin,
                                                     float* __restrict__ part,
                                                     int C, int R) {
    const int bid = blockIdx.x;
    const int b = bid / C, c = bid % C;
    const int w = threadIdx.x >> 6;       // wave 0..3
    const int lane = threadIdx.x & 63;
    const int dq = lane >> 3;             // owns d in [8dq, 8dq+8)
    const int eq = lane & 7;              // owns e in [8eq, 8eq+8)

    const int rows_per_wave = R >> 2;     // R/4
    const size_t row0 = (size_t)b * N_ + (size_t)c * R + (size_t)w * rows_per_wave;
    const float* kbase = kin + row0 * D_ + 8 * dq;
    const float* vbase = vin + row0 * D_ + 8 * eq;

    float acc[8][8];
#pragma unroll
    for (int i = 0; i < 8; ++i)
#pragma unroll
        for (int jj = 0; jj < 8; ++jj) acc[i][jj] = 0.0f;

    for (int r = 0; r < rows_per_wave; r += 2) {
        // two rows in flight for load ILP
        const float4 ka0 = *(const float4*)(kbase + (size_t)(r + 0) * D_);
        const float4 kb0 = *(const float4*)(kbase + (size_t)(r + 0) * D_ + 4);
        const float4 va0 = *(const float4*)(vbase + (size_t)(r + 0) * D_);
        const float4 vb0 = *(const float4*)(vbase + (size_t)(r + 0) * D_ + 4);
        const float4 ka1 = *(const float4*)(kbase + (size_t)(r + 1) * D_);
        const float4 kb1 = *(const float4*)(kbase + (size_t)(r + 1) * D_ + 4);
        const float4 va1 = *(const float4*)(vbase + (size_t)(r + 1) * D_);
        const float4 vb1 = *(const float4*)(vbase + (size_t)(r + 1) * D_ + 4);

        const float kk0[8] = {elu1(ka0.x), elu1(ka0.y), elu1(ka0.z), elu1(ka0.w),
                              elu1(kb0.x), elu1(kb0.y), elu1(kb0.z), elu1(kb0.w)};
        const float vv0[8] = {va0.x, va0.y, va0.z, va0.w, vb0.x, vb0.y, vb0.z, vb0.w};
#pragma unroll
        for (int i = 0; i < 8; ++i)
#pragma unroll
            for (int jj = 0; jj < 8; ++jj)
                acc[i][jj] = __fmaf_rn(kk0[i], vv0[jj], acc[i][jj]);

        const float kk1[8] = {elu1(ka1.x), elu1(ka1.y), elu1(ka1.z), elu1(ka1.w),
                              elu1(kb1.x), elu1(kb1.y), elu1(kb1.z), elu1(kb1.w)};
        const float vv1[8] = {va1.x, va1.y, va1.z, va1.w, vb1.x, vb1.y, vb1.z, vb1.w};
#pragma unroll
        for (int i = 0; i < 8; ++i)
#pragma unroll
            for (int jj = 0; jj < 8; ++jj)
                acc[i][jj] = __fmaf_rn(kk1[i], vv1[jj], acc[i][jj]);
    }

    // cross-wave reduction in LDS (layout d*64+e); serial over 4 waves
    __shared__ float red[D_ * D_];
    for (int ww = 0; ww < 4; ++ww) {
        if (w == ww) {
#pragma unroll
            for (int i = 0; i < 8; ++i)
#pragma unroll
                for (int jq = 0; jq < 2; ++jq) {
                    float* p = &red[(8 * dq + i) * D_ + 8 * eq + 4 * jq];
                    if (ww == 0) {
                        float4 o = {acc[i][4 * jq + 0], acc[i][4 * jq + 1],
                                    acc[i][4 * jq + 2], acc[i][4 * jq + 3]};
                        *(float4*)p = o;
                    } else {
                        float4 cur = *(const float4*)p;
                        float4 o = {cur.x + acc[i][4 * jq + 0], cur.y + acc[i][4 * jq + 1],
                                    cur.z + acc[i][4 * jq + 2], cur.w + acc[i][4 * jq + 3]};
                        *(float4*)p = o;
                    }
                }
        }
        __syncthreads();
    }

    float4* pb = (float4*)(part + (size_t)bid * (D_ * D_));
    const float4* rp = (const float4*)red;
#pragma unroll
    for (int u = 0; u < 4; ++u)
        pb[threadIdx.x + 256 * u] = rp[threadIdx.x + 256 * u];
}

// ---------------------------------------------------------------------------
// Atomic fallback (only if ws too small for partials): needs ws pre-zeroed.
// ---------------------------------------------------------------------------
template <int TI>
__global__ __launch_bounds__(256) void k1_atomic(const float* __restrict__ kin,
                                                 const float* __restrict__ vin,
                                                 float* __restrict__ kv,
                                                 int C, int R) {
    const int bid = blockIdx.x;
    const int b = bid / C, c = bid % C;
    const size_t base = ((size_t)b * N_ + (size_t)c * R) * D_;
    const float4* kp = (const float4*)(kin + base);
    const float4* vp = (const float4*)(vin + base);

    __shared__ float lk[TI][D_];
    __shared__ float lv[TI][D_];

    const int tid = threadIdx.x;
    const int td = tid >> 4;
    const int te = tid & 15;

    float acc[4][4];
#pragma unroll
    for (int i = 0; i < 4; ++i)
#pragma unroll
        for (int j = 0; j < 4; ++j) acc[i][j] = 0.0f;

    const int ntiles = R / TI;
    for (int t = 0; t < ntiles; ++t) {
#pragma unroll
        for (int u = tid; u < TI * (D_ / 4); u += 256) {
            float4 kk = kp[t * TI * (D_ / 4) + u];
            float4 vv = vp[t * TI * (D_ / 4) + u];
            const int r = u >> 4, cc = (u & 15) * 4;
            float4 ek;
            ek.x = elu1(kk.x); ek.y = elu1(kk.y);
            ek.z = elu1(kk.z); ek.w = elu1(kk.w);
            *(float4*)&lk[r][cc] = ek;
            *(float4*)&lv[r][cc] = vv;
        }
        __syncthreads();
#pragma unroll 8
        for (int r = 0; r < TI; ++r) {
            const float4 kk = *(const float4*)&lk[r][td * 4];
            const float4 vv = *(const float4*)&lv[r][te * 4];
            const float kd[4] = {kk.x, kk.y, kk.z, kk.w};
            const float ve[4] = {vv.x, vv.y, vv.z, vv.w};
#pragma unroll
            for (int i = 0; i < 4; ++i)
#pragma unroll
                for (int j = 0; j < 4; ++j)
                    acc[i][j] = __fmaf_rn(kd[i], ve[j], acc[i][j]);
        }
        __syncthreads();
    }

    float* pb = kv + (size_t)b * (D_ * D_);
#pragma unroll
    for (int i = 0; i < 4; ++i)
#pragma unroll
        for (int j = 0; j < 4; ++j)
            atomicAdd(&pb[(4 * td + i) * D_ + 4 * te + j], acc[i][j]);
}

// ---------------------------------------------------------------------------
// Pass 1b: reduce C partials -> final KV written in-place to chunk 0.
// 4-way independent partial sums for load pipelining.
// ---------------------------------------------------------------------------
__global__ __launch_bounds__(256) void k2_reduce(float* __restrict__ part, int C) {
    const int i = blockIdx.x * 256 + threadIdx.x;  // 0 .. B_*4096-1
    const int b = i >> 12, jj = i & 4095;
    float* p = part + (size_t)b * C * (D_ * D_) + jj;
    float s0 = 0.0f, s1 = 0.0f, s2 = 0.0f, s3 = 0.0f;
    int c = 0;
    for (; c + 4 <= C; c += 4) {
        s0 += p[(size_t)(c + 0) * (D_ * D_)];
        s1 += p[(size_t)(c + 1) * (D_ * D_)];
        s2 += p[(size_t)(c + 2) * (D_ * D_)];
        s3 += p[(size_t)(c + 3) * (D_ * D_)];
    }
    for (; c < C; ++c) s0 += p[(size_t)c * (D_ * D_)];
    p[0] = (s0 + s1) + (s2 + s3);
}

// ---------------------------------------------------------------------------
// Pass 2 (v2): out[b,n,:] = phi(q[b,n,:]) @ KV[b] * (1/(D*N)).
// 4 lanes per row; interleaved e-quad ownership -> lane-unit-stride 16B
// stores (full 64B lines, no write amplification). KV staged in LDS.
// ---------------------------------------------------------------------------
__global__ __launch_bounds__(256, 4) void k3_out(const float* __restrict__ q,
                                                 const float* __restrict__ kvbuf,
                                                 int kvstride,
                                                 float* __restrict__ out) {
    __shared__ float skv[D_ * D_];
    const int b = blockIdx.x >> 7;        // 128 blocks per batch
    const int tile = blockIdx.x & 127;

    // stage KV coalesced
    const float4* kvg = (const float4*)(kvbuf + (size_t)b * kvstride);
    float4* skv4 = (float4*)skv;
#pragma unroll
    for (int u = 0; u < 4; ++u)
        skv4[threadIdx.x + 256 * u] = kvg[threadIdx.x + 256 * u];

    const int r = threadIdx.x >> 2;       // 0..63 local row
    const int j = threadIdx.x & 3;
    const size_t row = (size_t)b * N_ + (size_t)tile * 64 + r;

    // load this lane's 16 q values (contiguous 64B) + elu
    const float4* qp = (const float4*)(q + row * D_ + j * 16);
    float qf[16];
#pragma unroll
    for (int u = 0; u < 4; ++u) {
        float4 t = qp[u];
        qf[4 * u + 0] = elu1(t.x);
        qf[4 * u + 1] = elu1(t.y);
        qf[4 * u + 2] = elu1(t.z);
        qf[4 * u + 3] = elu1(t.w);
    }
    __syncthreads();

    float4 acc[4];
#pragma unroll
    for (int s = 0; s < 4; ++s) acc[s] = {0.0f, 0.0f, 0.0f, 0.0f};

    for (int d0 = 0; d0 < 4; ++d0) {
        const int dbase = d0 * 16;
#pragma unroll
        for (int dd = 0; dd < 16; ++dd) {
            // qf[d] owner lane = d0 (uniform), local index dd (static)
            const float qd = __shfl(qf[dd], d0, 4);
            const int d = dbase + dd;
#pragma unroll
            for (int s = 0; s < 4; ++s) {
                const float4 kvv = *(const float4*)&skv[d * D_ + s * 16 + j * 4];
                acc[s].x = __fmaf_rn(qd, kvv.x, acc[s].x);
                acc[s].y = __fmaf_rn(qd, kvv.y, acc[s].y);
                acc[s].z = __fmaf_rn(qd, kvv.z, acc[s].z);
                acc[s].w = __fmaf_rn(qd, kvv.w, acc[s].w);
            }
        }
    }

    const float scale = 1.0f / (float)((size_t)D_ * N_);
    float4* op = (float4*)(out + row * D_);
#pragma unroll
    for (int s = 0; s < 4; ++s) {
        float4 o = {acc[s].x * scale, acc[s].y * scale,
                    acc[s].z * scale, acc[s].w * scale};
        op[s * 4 + j] = o;   // e-quad (4j+16s) -> float4 index s*4+j
    }
}

extern "C" void kernel_launch(void* const* d_in, const int* in_sizes, int n_in,
                              void* d_out, int out_size, void* d_ws, size_t ws_size,
                              hipStream_t stream) {
    const float* q = (const float*)d_in[0];
    const float* k = (const float*)d_in[1];
    const float* v = (const float*)d_in[2];
    float* out = (float*)d_out;
    float* ws = (float*)d_ws;

    const size_t mat = (size_t)D_ * D_;  // 4096 floats per KV matrix

    // pick largest chunk count whose partial buffer fits in ws
    int C = 0;
    for (int cc = 64; cc >= 2; cc >>= 1) {
        if (ws_size >= (size_t)B_ * cc * mat * sizeof(float)) { C = cc; break; }
    }

    if (C >= 2) {
        const int R = N_ / C;
        k1_partial<<<B_ * C, 256, 0, stream>>>(k, v, ws, C, R);
        k2_reduce<<<(int)(B_ * mat) / 256, 256, 0, stream>>>(ws, C);
        k3_out<<<B_ * (N_ / 64), 256, 0, stream>>>(q, ws, (int)(C * mat), out);
    } else {
        // tiny-ws fallback: zero KV then atomically accumulate
        hipMemsetAsync(d_ws, 0, B_ * mat * sizeof(float), stream);
        const int C2 = 64, R = N_ / C2;
        k1_atomic<32><<<B_ * C2, 256, 0, stream>>>(k, v, ws, C2, R);
        k3_out<<<B_ * (N_ / 64), 256, 0, stream>>>(q, ws, (int)mat, out);
    }
}